// Round 3
// baseline (902.669 us; speedup 1.0000x reference)
//
#include <hip/hip_runtime.h>
#include <math.h>

#define NN 30000
#define EE 480000
#define AVG_D_LOG 2.833f
#define EPSF 1e-5f

__device__ __forceinline__ void fma4(float4& acc, float a, float4 w) {
    acc.x = fmaf(a, w.x, acc.x); acc.y = fmaf(a, w.y, acc.y);
    acc.z = fmaf(a, w.z, acc.z); acc.w = fmaf(a, w.w, acc.w);
}

// ---------------- CSR build ----------------
__global__ void k_deg(const int* __restrict__ dst, int* __restrict__ deg) {
    int i = blockIdx.x * blockDim.x + threadIdx.x;
    if (i < EE) atomicAdd(&deg[dst[i]], 1);
}

__global__ void k_scan(const int* __restrict__ deg, int* __restrict__ rowptr,
                       int* __restrict__ cursor) {
    __shared__ int ts[1024];
    int t = threadIdx.x;
    const int CH = 30;                 // 1024*30 = 30720 >= 30000
    int base = t * CH;
    int s = 0;
    for (int i = 0; i < CH; ++i) {
        int idx = base + i;
        if (idx < NN) s += deg[idx];
    }
    ts[t] = s;
    __syncthreads();
    for (int off = 1; off < 1024; off <<= 1) {
        int v = (t >= off) ? ts[t - off] : 0;
        __syncthreads();
        ts[t] += v;
        __syncthreads();
    }
    int run = (t == 0) ? 0 : ts[t - 1];
    for (int i = 0; i < CH; ++i) {
        int idx = base + i;
        if (idx < NN) {
            rowptr[idx] = run;
            cursor[idx] = run;
            run += deg[idx];
        }
    }
    if (t == 1023) rowptr[NN] = ts[1023];
}

// scatter edge ids into CSR order + tiny eig-filter MLP -> wl[e]
__global__ void k_scatter(const int* __restrict__ src, const int* __restrict__ dst,
                          const float* __restrict__ eig,
                          const float* __restrict__ W1, const float* __restrict__ b1,
                          const float* __restrict__ W2, const float* __restrict__ b2,
                          const float* __restrict__ W3, const float* __restrict__ b3,
                          int* __restrict__ cursor, int* __restrict__ edge_id,
                          float* __restrict__ wl) {
    int i = blockIdx.x * blockDim.x + threadIdx.x;
    if (i >= EE) return;
    int dd = dst[i];
    int pos = atomicAdd(&cursor[dd], 1);
    edge_id[pos] = i;

    int ss = src[i];
    float x[6];
    x[0] = eig[ss * 4 + 1]; x[1] = eig[ss * 4 + 2]; x[2] = eig[ss * 4 + 3];
    x[3] = eig[dd * 4 + 1]; x[4] = eig[dd * 4 + 2]; x[5] = eig[dd * 4 + 3];
    float a[3], bt[3];
    #pragma unroll
    for (int c = 0; c < 3; ++c) {
        float acc = b1[c];
        #pragma unroll
        for (int r = 0; r < 6; ++r) acc += x[r] * W1[r * 3 + c];
        a[c] = fmaxf(acc, 0.f);
    }
    #pragma unroll
    for (int c = 0; c < 3; ++c) {
        float acc = b2[c];
        #pragma unroll
        for (int r = 0; r < 3; ++r) acc += a[r] * W2[r * 3 + c];
        bt[c] = fmaxf(acc, 0.f);
    }
    float y = b3[0];
    #pragma unroll
    for (int r = 0; r < 3; ++r) y += bt[r] * W3[r];
    wl[i] = 1.f / (1.f + expf(-y));
}

// ---------------- k_pre: U = h @ W_pre[0:128], V = h @ W_pre[128:256] ----------------
// 16 nodes/block, 256 threads: jg=tid&31 -> 4 cols, rg=tid>>5 -> rows rg, rg+8.
__global__ __launch_bounds__(256) void k_pre(const float* __restrict__ h,
                                             const float* __restrict__ Wp,
                                             float* __restrict__ U,
                                             float* __restrict__ V) {
    __shared__ float At[16][128];
    int tid = threadIdx.x;
    int v0 = blockIdx.x * 16;           // grid exact: 1875*16 == 30000
    const float4* h4 = (const float4*)h;
    for (int i = tid; i < 16 * 32; i += 256) {
        int r = i >> 5, kq = i & 31;
        ((float4*)&At[r][0])[kq] = h4[(size_t)(v0 + r) * 32 + kq];
    }
    __syncthreads();

    int jg = tid & 31, rg = tid >> 5;
    int j4 = jg * 4;
    float4 aU[2], aV[2];
    aU[0] = make_float4(0,0,0,0); aU[1] = make_float4(0,0,0,0);
    aV[0] = make_float4(0,0,0,0); aV[1] = make_float4(0,0,0,0);

    #pragma unroll 4
    for (int k = 0; k < 128; ++k) {
        float4 wu = *(const float4*)(Wp + (size_t)k * 128 + j4);
        float4 wv = *(const float4*)(Wp + (size_t)(k + 128) * 128 + j4);
        float a0 = At[rg][k], a1 = At[rg + 8][k];
        fma4(aU[0], a0, wu); fma4(aU[1], a1, wu);
        fma4(aV[0], a0, wv); fma4(aV[1], a1, wv);
    }
    #pragma unroll
    for (int r = 0; r < 2; ++r) {
        int v = v0 + rg + r * 8;
        *(float4*)(U + (size_t)v * 128 + j4) = aU[r];
        *(float4*)(V + (size_t)v * 128 + j4) = aV[r];
    }
}

// ---------------- k_fused: edge aggregation (into LDS) + post GEMM ----------------
// Block = 16 nodes, 256 threads.
// Phase 1 (4 waves, 4 nodes each): e = U[src]+V[v]+ef@W_ef+b, five segment
//   reductions, agg row written straight into At[r][128:768).
// Phase 2: out = h@Wh + agg@W1 + f1*(agg@W2) + f2*(agg@W3); jg=tid&31 -> 4 cols
//   (float4 W loads), rg=tid>>5 -> rows rg, rg+8 (broadcast LDS A reads).
// redS/redQ alias the dead At tile after a barrier (LDS 49.4 KB -> 3 blocks/CU).
__global__ __launch_bounds__(256) void k_fused(
    const float* __restrict__ h, const float* __restrict__ U,
    const float* __restrict__ V, const float* __restrict__ ef,
    const float* __restrict__ b_pre, const float* __restrict__ W_pre,
    const int* __restrict__ src, const int* __restrict__ rowptr,
    const int* __restrict__ edge_id, const float* __restrict__ wl,
    const float* __restrict__ Wp, const float* __restrict__ bpost,
    const float* __restrict__ snorm, float* __restrict__ out,
    float* __restrict__ colsum, float* __restrict__ colsq) {
    __shared__ float At[16][768];      // [r][0:128)=h row, [r][128:768)=agg row
    __shared__ float f1s[16], f2s[16];
    int tid = threadIdx.x;
    int v0 = blockIdx.x * 16;          // grid exact: 1875*16 == 30000

    // h tile -> At[:,0:128)   (no barrier needed vs phase 1: disjoint LDS cols)
    const float4* h4 = (const float4*)h;
    for (int i = tid; i < 16 * 32; i += 256) {
        int r = i >> 5, kq = i & 31;
        ((float4*)&At[r][0])[kq] = h4[(size_t)(v0 + r) * 32 + kq];
    }

    // ---- phase 1: aggregation, wave w owns rows 4w..4w+3 ----
    const int wave = tid >> 6, lane = tid & 63;
    float wef0[16], wef1[16];
    #pragma unroll
    for (int k = 0; k < 16; ++k) {
        wef0[k] = W_pre[(size_t)(256 + k) * 128 + lane];
        wef1[k] = W_pre[(size_t)(256 + k) * 128 + 64 + lane];
    }
    const float b0 = b_pre[lane], b1 = b_pre[lane + 64];

    for (int i = 0; i < 4; ++i) {
        int r = wave * 4 + i;
        int v = v0 + r;
        int rs = rowptr[v];
        int d  = rowptr[v + 1] - rs;

        float pd0 = V[(size_t)v * 128 + lane] + b0;
        float pd1 = V[(size_t)v * 128 + 64 + lane] + b1;

        float sum0 = 0.f, sum1 = 0.f, sq0 = 0.f, sq1 = 0.f, el0 = 0.f, el1 = 0.f;
        float mx0 = -INFINITY, mx1 = -INFINITY, mn0 = INFINITY, mn1 = INFINITY;

        int eid_n = (d > 0) ? edge_id[rs] : 0;
        for (int t = 0; t < d; ++t) {
            int eid = eid_n;
            if (t + 1 < d) eid_n = edge_id[rs + t + 1];   // 1-deep prefetch
            int s   = src[eid];
            float w = wl[eid];
            float u0 = U[(size_t)s * 128 + lane];
            float u1 = U[(size_t)s * 128 + 64 + lane];
            const float4* e4 = (const float4*)(ef + (size_t)eid * 16);
            float4 q0 = e4[0], q1 = e4[1], q2 = e4[2], q3 = e4[3];

            float ef0 = q0.x * wef0[0] + q0.y * wef0[1] + q0.z * wef0[2] + q0.w * wef0[3]
                      + q1.x * wef0[4] + q1.y * wef0[5] + q1.z * wef0[6] + q1.w * wef0[7]
                      + q2.x * wef0[8] + q2.y * wef0[9] + q2.z * wef0[10] + q2.w * wef0[11]
                      + q3.x * wef0[12] + q3.y * wef0[13] + q3.z * wef0[14] + q3.w * wef0[15];
            float ef1 = q0.x * wef1[0] + q0.y * wef1[1] + q0.z * wef1[2] + q0.w * wef1[3]
                      + q1.x * wef1[4] + q1.y * wef1[5] + q1.z * wef1[6] + q1.w * wef1[7]
                      + q2.x * wef1[8] + q2.y * wef1[9] + q2.z * wef1[10] + q2.w * wef1[11]
                      + q3.x * wef1[12] + q3.y * wef1[13] + q3.z * wef1[14] + q3.w * wef1[15];

            float e0 = pd0 + u0 + ef0;
            float e1 = pd1 + u1 + ef1;
            sum0 += e0; sum1 += e1;
            sq0 = fmaf(e0, e0, sq0); sq1 = fmaf(e1, e1, sq1);
            mx0 = fmaxf(mx0, e0); mx1 = fmaxf(mx1, e1);
            mn0 = fminf(mn0, e0); mn1 = fminf(mn1, e1);
            el0 = fmaf(e0, w, el0); el1 = fmaf(e1, w, el1);
        }

        float* Ar = &At[r][128];       // agg = [mean|max|min|std|el] x 128
        if (d > 0) {
            float inv = 1.f / (float)d;
            float m0 = sum0 * inv, m1 = sum1 * inv;
            float vv0 = fmaxf(sq0 * inv - m0 * m0, 0.f);
            float vv1 = fmaxf(sq1 * inv - m1 * m1, 0.f);
            Ar[lane]       = m0;  Ar[64 + lane]  = m1;
            Ar[128 + lane] = mx0; Ar[192 + lane] = mx1;
            Ar[256 + lane] = mn0; Ar[320 + lane] = mn1;
            Ar[384 + lane] = sqrtf(vv0 + EPSF); Ar[448 + lane] = sqrtf(vv1 + EPSF);
            Ar[512 + lane] = el0; Ar[576 + lane] = el1;
            if (lane == 0) {
                float ld = logf((float)d + 1.f);
                f1s[r] = ld / AVG_D_LOG;
                f2s[r] = AVG_D_LOG / ld;
            }
        } else {
            #pragma unroll
            for (int s5 = 0; s5 < 5; ++s5) {
                Ar[s5 * 128 + lane] = 0.f;
                Ar[s5 * 128 + 64 + lane] = 0.f;
            }
            if (lane == 0) { f1s[r] = 0.f; f2s[r] = 0.f; }
        }
    }
    __syncthreads();

    // ---- phase 2: GEMM ----
    int jg = tid & 31, rg = tid >> 5;
    int j4 = jg * 4;
    float4 acc0[2], acc1[2], acc2[2];
    acc0[0] = make_float4(0,0,0,0); acc0[1] = make_float4(0,0,0,0);
    acc1[0] = make_float4(0,0,0,0); acc1[1] = make_float4(0,0,0,0);
    acc2[0] = make_float4(0,0,0,0); acc2[1] = make_float4(0,0,0,0);

    // h block: W rows [0,128)
    #pragma unroll 4
    for (int k = 0; k < 128; ++k) {
        float4 w0 = *(const float4*)(Wp + (size_t)k * 128 + j4);
        float a0 = At[rg][k], a1 = At[rg + 8][k];
        fma4(acc0[0], a0, w0); fma4(acc0[1], a1, w0);
    }
    // agg block: W rows [128,768) + [768,1408) (f1) + [1408,2048) (f2)
    #pragma unroll 2
    for (int k = 128; k < 768; ++k) {
        float4 w0 = *(const float4*)(Wp + (size_t)k * 128 + j4);
        float4 w1 = *(const float4*)(Wp + (size_t)(k + 640) * 128 + j4);
        float4 w2 = *(const float4*)(Wp + (size_t)(k + 1280) * 128 + j4);
        float a0 = At[rg][k], a1 = At[rg + 8][k];
        fma4(acc0[0], a0, w0); fma4(acc0[1], a1, w0);
        fma4(acc1[0], a0, w1); fma4(acc1[1], a1, w1);
        fma4(acc2[0], a0, w2); fma4(acc2[1], a1, w2);
    }

    float4 bj = *(const float4*)(bpost + j4);
    float ps[4] = {0.f, 0.f, 0.f, 0.f}, pq[4] = {0.f, 0.f, 0.f, 0.f};
    #pragma unroll
    for (int r2 = 0; r2 < 2; ++r2) {
        int r = rg + r2 * 8;
        int v = v0 + r;
        float f1 = f1s[r], f2 = f2s[r], sn = snorm[v];
        float4 o;
        o.x = (acc0[r2].x + bj.x + f1 * acc1[r2].x + f2 * acc2[r2].x) * sn;
        o.y = (acc0[r2].y + bj.y + f1 * acc1[r2].y + f2 * acc2[r2].y) * sn;
        o.z = (acc0[r2].z + bj.z + f1 * acc1[r2].z + f2 * acc2[r2].z) * sn;
        o.w = (acc0[r2].w + bj.w + f1 * acc1[r2].w + f2 * acc2[r2].w) * sn;
        *(float4*)(out + (size_t)v * 128 + j4) = o;
        ps[0] += o.x; pq[0] += o.x * o.x;
        ps[1] += o.y; pq[1] += o.y * o.y;
        ps[2] += o.z; pq[2] += o.z * o.z;
        ps[3] += o.w; pq[3] += o.w * o.w;
    }

    __syncthreads();                    // all At reads complete
    float* redS = &At[0][0];            // alias dead A-tile: [8][128]
    float* redQ = redS + 1024;          // [8][128]
    #pragma unroll
    for (int c = 0; c < 4; ++c) {
        redS[rg * 128 + j4 + c] = ps[c];
        redQ[rg * 128 + j4 + c] = pq[c];
    }
    __syncthreads();
    if (tid < 128) {
        float s = 0.f, q = 0.f;
        #pragma unroll
        for (int g = 0; g < 8; ++g) { s += redS[g * 128 + tid]; q += redQ[g * 128 + tid]; }
        atomicAdd(&colsum[tid], s);
        atomicAdd(&colsq[tid], q);
    }
}

// ---------------- column batch-norm ----------------
__global__ void k_norm(float* __restrict__ out, const float* __restrict__ colsum,
                       const float* __restrict__ colsq, const float* __restrict__ gamma,
                       const float* __restrict__ beta) {
    int i = blockIdx.x * 256 + threadIdx.x;
    if (i >= NN * 128) return;
    int j = i & 127;
    float mu = colsum[j] * (1.f / NN);
    float var = fmaxf(colsq[j] * (1.f / NN) - mu * mu, 0.f);
    float inv = 1.f / sqrtf(var + 1e-5f);
    out[i] = (out[i] - mu) * inv * gamma[j] + beta[j];
}

static inline size_t align256(size_t x) { return (x + 255) & ~(size_t)255; }

extern "C" void kernel_launch(void* const* d_in, const int* in_sizes, int n_in,
                              void* d_out, int out_size, void* d_ws, size_t ws_size,
                              hipStream_t stream) {
    const float* h      = (const float*)d_in[0];
    const float* eig    = (const float*)d_in[1];
    const float* ef     = (const float*)d_in[2];
    const int*   src    = (const int*)d_in[3];
    const int*   dst    = (const int*)d_in[4];
    const float* snorm  = (const float*)d_in[5];
    const float* W_pre  = (const float*)d_in[6];
    const float* b_pre  = (const float*)d_in[7];
    const float* ftW1   = (const float*)d_in[8];
    const float* ftb1   = (const float*)d_in[9];
    const float* ftW2   = (const float*)d_in[10];
    const float* ftb2   = (const float*)d_in[11];
    const float* ftW3   = (const float*)d_in[12];
    const float* ftb3   = (const float*)d_in[13];
    const float* W_post = (const float*)d_in[14];
    const float* b_post = (const float*)d_in[15];
    const float* gamma  = (const float*)d_in[16];
    const float* beta   = (const float*)d_in[17];
    float* out = (float*)d_out;

    char* ws = (char*)d_ws;
    size_t off = 0;
    int* rowptr  = (int*)(ws + off); off += align256((NN + 1) * 4);
    int* cursor  = (int*)(ws + off); off += align256(NN * 4);
    int* deg     = (int*)(ws + off); off += align256(NN * 4);
    int* edge_id = (int*)(ws + off); off += align256((size_t)EE * 4);
    float* wl    = (float*)(ws + off); off += align256((size_t)EE * 4);
    float* colsum = (float*)(ws + off); off += 512;
    float* colsq  = (float*)(ws + off); off += 512;
    float* U     = (float*)(ws + off); off += (size_t)NN * 128 * 4;
    float* V     = (float*)(ws + off); off += (size_t)NN * 128 * 4;
    // total ~= 35 MB

    hipMemsetAsync(deg, 0, NN * 4, stream);
    hipMemsetAsync(colsum, 0, 1024, stream);   // colsum + colsq contiguous

    k_deg<<<1875, 256, 0, stream>>>(dst, deg);
    k_scan<<<1, 1024, 0, stream>>>(deg, rowptr, cursor);
    k_scatter<<<1875, 256, 0, stream>>>(src, dst, eig, ftW1, ftb1, ftW2, ftb2,
                                        ftW3, ftb3, cursor, edge_id, wl);
    k_pre<<<1875, 256, 0, stream>>>(h, W_pre, U, V);
    k_fused<<<1875, 256, 0, stream>>>(h, U, V, ef, b_pre, W_pre, src, rowptr,
                                      edge_id, wl, W_post, b_post, snorm, out,
                                      colsum, colsq);
    k_norm<<<15000, 256, 0, stream>>>(out, colsum, colsq, gamma, beta);
}

// Round 4
// 825.033 us; speedup vs baseline: 1.0941x; 1.0941x over previous
//
#include <hip/hip_runtime.h>
#include <math.h>

#define NN 30000
#define EE 480000
#define AVG_D_LOG 2.833f
#define EPSF 1e-5f
#define ATP 772            // padded LDS row: 768+4 (breaks 8-way bank conflict)

__device__ __forceinline__ void fma4(float4& acc, float a, float4 w) {
    acc.x = fmaf(a, w.x, acc.x); acc.y = fmaf(a, w.y, acc.y);
    acc.z = fmaf(a, w.z, acc.z); acc.w = fmaf(a, w.w, acc.w);
}

// ---------------- CSR build ----------------
__global__ void k_deg(const int* __restrict__ dst, int* __restrict__ deg) {
    int i = blockIdx.x * blockDim.x + threadIdx.x;
    if (i < EE) atomicAdd(&deg[dst[i]], 1);
}

__global__ void k_scan(const int* __restrict__ deg, int* __restrict__ rowptr,
                       int* __restrict__ cursor) {
    __shared__ int ts[1024];
    int t = threadIdx.x;
    const int CH = 30;                 // 1024*30 = 30720 >= 30000
    int base = t * CH;
    int s = 0;
    for (int i = 0; i < CH; ++i) {
        int idx = base + i;
        if (idx < NN) s += deg[idx];
    }
    ts[t] = s;
    __syncthreads();
    for (int off = 1; off < 1024; off <<= 1) {
        int v = (t >= off) ? ts[t - off] : 0;
        __syncthreads();
        ts[t] += v;
        __syncthreads();
    }
    int run = (t == 0) ? 0 : ts[t - 1];
    for (int i = 0; i < CH; ++i) {
        int idx = base + i;
        if (idx < NN) {
            rowptr[idx] = run;
            cursor[idx] = run;
            run += deg[idx];
        }
    }
    if (t == 1023) rowptr[NN] = ts[1023];
}

// scatter CSR-ordered per-edge records {src, eid, wl}; wl = eig-filter MLP
__global__ void k_scatter(const int* __restrict__ src, const int* __restrict__ dst,
                          const float* __restrict__ eig,
                          const float* __restrict__ W1, const float* __restrict__ b1,
                          const float* __restrict__ W2, const float* __restrict__ b2,
                          const float* __restrict__ W3, const float* __restrict__ b3,
                          int* __restrict__ cursor, int* __restrict__ csr_src,
                          int* __restrict__ csr_eid, float* __restrict__ csr_wl) {
    int i = blockIdx.x * blockDim.x + threadIdx.x;
    if (i >= EE) return;
    int dd = dst[i];
    int ss = src[i];
    int pos = atomicAdd(&cursor[dd], 1);
    csr_src[pos] = ss;
    csr_eid[pos] = i;

    float x[6];
    x[0] = eig[ss * 4 + 1]; x[1] = eig[ss * 4 + 2]; x[2] = eig[ss * 4 + 3];
    x[3] = eig[dd * 4 + 1]; x[4] = eig[dd * 4 + 2]; x[5] = eig[dd * 4 + 3];
    float a[3], bt[3];
    #pragma unroll
    for (int c = 0; c < 3; ++c) {
        float acc = b1[c];
        #pragma unroll
        for (int r = 0; r < 6; ++r) acc += x[r] * W1[r * 3 + c];
        a[c] = fmaxf(acc, 0.f);
    }
    #pragma unroll
    for (int c = 0; c < 3; ++c) {
        float acc = b2[c];
        #pragma unroll
        for (int r = 0; r < 3; ++r) acc += a[r] * W2[r * 3 + c];
        bt[c] = fmaxf(acc, 0.f);
    }
    float y = b3[0];
    #pragma unroll
    for (int r = 0; r < 3; ++r) y += bt[r] * W3[r];
    csr_wl[pos] = 1.f / (1.f + expf(-y));
}

// ---------------- k_pre: U = h @ W_pre[0:128], V = h @ W_pre[128:256] ----------------
// Wave w owns 32 cols [32w,32w+32): no intra-block W duplication (256 KB/block).
__global__ __launch_bounds__(256) void k_pre(const float* __restrict__ h,
                                             const float* __restrict__ Wp,
                                             float* __restrict__ U,
                                             float* __restrict__ V) {
    __shared__ float At[16][132];      // pad: 132%32=4 -> 8 rows hit 8 banks
    int tid = threadIdx.x;
    int v0 = blockIdx.x * 16;          // grid exact: 1875*16 == 30000
    const float4* h4 = (const float4*)h;
    for (int i = tid; i < 16 * 32; i += 256) {
        int r = i >> 5, kq = i & 31;
        ((float4*)&At[r][0])[kq] = h4[(size_t)(v0 + r) * 32 + kq];
    }
    __syncthreads();

    int wave = tid >> 6, lane = tid & 63;
    int jloc = lane & 7, rrow = lane >> 3;
    int j4 = wave * 32 + jloc * 4;
    float4 aU[2], aV[2];
    aU[0] = make_float4(0,0,0,0); aU[1] = make_float4(0,0,0,0);
    aV[0] = make_float4(0,0,0,0); aV[1] = make_float4(0,0,0,0);

    #pragma unroll 4
    for (int k = 0; k < 128; ++k) {
        float4 wu = *(const float4*)(Wp + (size_t)k * 128 + j4);
        float4 wv = *(const float4*)(Wp + (size_t)(k + 128) * 128 + j4);
        float a0 = At[rrow][k], a1 = At[rrow + 8][k];
        fma4(aU[0], a0, wu); fma4(aU[1], a1, wu);
        fma4(aV[0], a0, wv); fma4(aV[1], a1, wv);
    }
    #pragma unroll
    for (int r = 0; r < 2; ++r) {
        int v = v0 + rrow + r * 8;
        *(float4*)(U + (size_t)v * 128 + j4) = aU[r];
        *(float4*)(V + (size_t)v * 128 + j4) = aV[r];
    }
}

// ---------------- k_fused: edge aggregation (into LDS) + post GEMM ----------------
__device__ __forceinline__ void proj_ef(const float4* __restrict__ q,
                                        const float wef0[16], const float wef1[16],
                                        float& p0, float& p1) {
    float4 qa = q[0], qb = q[1], qc = q[2], qd = q[3];
    p0 = qa.x*wef0[0] + qa.y*wef0[1] + qa.z*wef0[2] + qa.w*wef0[3]
       + qb.x*wef0[4] + qb.y*wef0[5] + qb.z*wef0[6] + qb.w*wef0[7]
       + qc.x*wef0[8] + qc.y*wef0[9] + qc.z*wef0[10] + qc.w*wef0[11]
       + qd.x*wef0[12] + qd.y*wef0[13] + qd.z*wef0[14] + qd.w*wef0[15];
    p1 = qa.x*wef1[0] + qa.y*wef1[1] + qa.z*wef1[2] + qa.w*wef1[3]
       + qb.x*wef1[4] + qb.y*wef1[5] + qb.z*wef1[6] + qb.w*wef1[7]
       + qc.x*wef1[8] + qc.y*wef1[9] + qc.z*wef1[10] + qc.w*wef1[11]
       + qd.x*wef1[12] + qd.y*wef1[13] + qd.z*wef1[14] + qd.w*wef1[15];
}

__global__ __launch_bounds__(256) void k_fused(
    const float* __restrict__ h, const float* __restrict__ U,
    const float* __restrict__ V, const float* __restrict__ ef,
    const float* __restrict__ b_pre, const float* __restrict__ W_pre,
    const int* __restrict__ csr_src, const int* __restrict__ rowptr,
    const int* __restrict__ csr_eid, const float* __restrict__ csr_wl,
    const float* __restrict__ Wp, const float* __restrict__ bpost,
    const float* __restrict__ snorm, float* __restrict__ out,
    float* __restrict__ colsum, float* __restrict__ colsq) {
    __shared__ float At[16][ATP];      // [r][0:128)=h, [r][128:768)=agg, pad 4
    __shared__ float f1s[16], f2s[16];
    int tid = threadIdx.x;
    int v0 = blockIdx.x * 16;          // grid exact: 1875*16 == 30000

    const float4* h4 = (const float4*)h;
    for (int i = tid; i < 16 * 32; i += 256) {
        int r = i >> 5, kq = i & 31;
        ((float4*)&At[r][0])[kq] = h4[(size_t)(v0 + r) * 32 + kq];
    }

    // ---- phase 1: aggregation, wave w owns rows 4w..4w+3 ----
    const int wave = __builtin_amdgcn_readfirstlane(tid >> 6);
    const int lane = tid & 63;
    float wef0[16], wef1[16];
    #pragma unroll
    for (int k = 0; k < 16; ++k) {
        wef0[k] = W_pre[(size_t)(256 + k) * 128 + lane];
        wef1[k] = W_pre[(size_t)(256 + k) * 128 + 64 + lane];
    }
    const float b0 = b_pre[lane], b1 = b_pre[lane + 64];

    for (int i = 0; i < 4; ++i) {
        int r = wave * 4 + i;
        int v = v0 + r;
        int rs = rowptr[v];
        int d  = rowptr[v + 1] - rs;

        float pd0 = V[(size_t)v * 128 + lane] + b0;
        float pd1 = V[(size_t)v * 128 + 64 + lane] + b1;

        float sum0 = 0.f, sum1 = 0.f, sq0 = 0.f, sq1 = 0.f, el0 = 0.f, el1 = 0.f;
        float mx0 = -INFINITY, mx1 = -INFINITY, mn0 = INFINITY, mn1 = INFINITY;

        int t = 0;
        // 4-wide batches: 8 U-row gathers in flight; metadata sequential/uniform
        for (; t + 4 <= d; t += 4) {
            int s0 = csr_src[rs+t+0], s1 = csr_src[rs+t+1];
            int s2 = csr_src[rs+t+2], s3 = csr_src[rs+t+3];
            int e0 = csr_eid[rs+t+0], e1 = csr_eid[rs+t+1];
            int e2 = csr_eid[rs+t+2], e3 = csr_eid[rs+t+3];
            float wl0 = csr_wl[rs+t+0], wl1 = csr_wl[rs+t+1];
            float wl2 = csr_wl[rs+t+2], wl3 = csr_wl[rs+t+3];
            const float* U0 = U + (size_t)s0 * 128;
            const float* U1 = U + (size_t)s1 * 128;
            const float* U2 = U + (size_t)s2 * 128;
            const float* U3 = U + (size_t)s3 * 128;
            float u00 = U0[lane], u01 = U0[64 + lane];
            float u10 = U1[lane], u11 = U1[64 + lane];
            float u20 = U2[lane], u21 = U2[64 + lane];
            float u30 = U3[lane], u31 = U3[64 + lane];

            float p0, p1;
            proj_ef((const float4*)(ef + (size_t)e0 * 16), wef0, wef1, p0, p1);
            {
                float ee0 = pd0 + u00 + p0, ee1 = pd1 + u01 + p1;
                sum0 += ee0; sum1 += ee1;
                sq0 = fmaf(ee0, ee0, sq0); sq1 = fmaf(ee1, ee1, sq1);
                mx0 = fmaxf(mx0, ee0); mx1 = fmaxf(mx1, ee1);
                mn0 = fminf(mn0, ee0); mn1 = fminf(mn1, ee1);
                el0 = fmaf(ee0, wl0, el0); el1 = fmaf(ee1, wl1 * 0.f + wl0, el1) ;
            }
            // NOTE: careful — el1 must use wl0 for edge 0. (kept explicit below)
            proj_ef((const float4*)(ef + (size_t)e1 * 16), wef0, wef1, p0, p1);
            {
                float ee0 = pd0 + u10 + p0, ee1 = pd1 + u11 + p1;
                sum0 += ee0; sum1 += ee1;
                sq0 = fmaf(ee0, ee0, sq0); sq1 = fmaf(ee1, ee1, sq1);
                mx0 = fmaxf(mx0, ee0); mx1 = fmaxf(mx1, ee1);
                mn0 = fminf(mn0, ee0); mn1 = fminf(mn1, ee1);
                el0 = fmaf(ee0, wl1, el0); el1 = fmaf(ee1, wl1, el1);
            }
            proj_ef((const float4*)(ef + (size_t)e2 * 16), wef0, wef1, p0, p1);
            {
                float ee0 = pd0 + u20 + p0, ee1 = pd1 + u21 + p1;
                sum0 += ee0; sum1 += ee1;
                sq0 = fmaf(ee0, ee0, sq0); sq1 = fmaf(ee1, ee1, sq1);
                mx0 = fmaxf(mx0, ee0); mx1 = fmaxf(mx1, ee1);
                mn0 = fminf(mn0, ee0); mn1 = fminf(mn1, ee1);
                el0 = fmaf(ee0, wl2, el0); el1 = fmaf(ee1, wl2, el1);
            }
            proj_ef((const float4*)(ef + (size_t)e3 * 16), wef0, wef1, p0, p1);
            {
                float ee0 = pd0 + u30 + p0, ee1 = pd1 + u31 + p1;
                sum0 += ee0; sum1 += ee1;
                sq0 = fmaf(ee0, ee0, sq0); sq1 = fmaf(ee1, ee1, sq1);
                mx0 = fmaxf(mx0, ee0); mx1 = fmaxf(mx1, ee1);
                mn0 = fminf(mn0, ee0); mn1 = fminf(mn1, ee1);
                el0 = fmaf(ee0, wl3, el0); el1 = fmaf(ee1, wl3, el1);
            }
        }
        for (; t < d; ++t) {
            int s0 = csr_src[rs + t];
            int e0 = csr_eid[rs + t];
            float wl0 = csr_wl[rs + t];
            const float* U0 = U + (size_t)s0 * 128;
            float u00 = U0[lane], u01 = U0[64 + lane];
            float p0, p1;
            proj_ef((const float4*)(ef + (size_t)e0 * 16), wef0, wef1, p0, p1);
            float ee0 = pd0 + u00 + p0, ee1 = pd1 + u01 + p1;
            sum0 += ee0; sum1 += ee1;
            sq0 = fmaf(ee0, ee0, sq0); sq1 = fmaf(ee1, ee1, sq1);
            mx0 = fmaxf(mx0, ee0); mx1 = fmaxf(mx1, ee1);
            mn0 = fminf(mn0, ee0); mn1 = fminf(mn1, ee1);
            el0 = fmaf(ee0, wl0, el0); el1 = fmaf(ee1, wl0, el1);
        }

        float* Ar = &At[r][128];       // agg = [mean|max|min|std|el] x 128
        if (d > 0) {
            float inv = 1.f / (float)d;
            float m0 = sum0 * inv, m1 = sum1 * inv;
            float vv0 = fmaxf(sq0 * inv - m0 * m0, 0.f);
            float vv1 = fmaxf(sq1 * inv - m1 * m1, 0.f);
            Ar[lane]       = m0;  Ar[64 + lane]  = m1;
            Ar[128 + lane] = mx0; Ar[192 + lane] = mx1;
            Ar[256 + lane] = mn0; Ar[320 + lane] = mn1;
            Ar[384 + lane] = sqrtf(vv0 + EPSF); Ar[448 + lane] = sqrtf(vv1 + EPSF);
            Ar[512 + lane] = el0; Ar[576 + lane] = el1;
            if (lane == 0) {
                float ld = logf((float)d + 1.f);
                f1s[r] = ld / AVG_D_LOG;
                f2s[r] = AVG_D_LOG / ld;
            }
        } else {
            #pragma unroll
            for (int s5 = 0; s5 < 5; ++s5) {
                Ar[s5 * 128 + lane] = 0.f;
                Ar[s5 * 128 + 64 + lane] = 0.f;
            }
            if (lane == 0) { f1s[r] = 0.f; f2s[r] = 0.f; }
        }
    }
    __syncthreads();

    // ---- phase 2: GEMM. Wave w owns 32 cols -> W traffic 1.05 MB/block ----
    int jloc = lane & 7, rrow = lane >> 3;
    int j4 = wave * 32 + jloc * 4;
    float4 acc0[2], acc1[2], acc2[2];
    acc0[0] = make_float4(0,0,0,0); acc0[1] = make_float4(0,0,0,0);
    acc1[0] = make_float4(0,0,0,0); acc1[1] = make_float4(0,0,0,0);
    acc2[0] = make_float4(0,0,0,0); acc2[1] = make_float4(0,0,0,0);

    #pragma unroll 4
    for (int k = 0; k < 128; ++k) {
        float4 w0 = *(const float4*)(Wp + (size_t)k * 128 + j4);
        float a0 = At[rrow][k], a1 = At[rrow + 8][k];
        fma4(acc0[0], a0, w0); fma4(acc0[1], a1, w0);
    }
    #pragma unroll 2
    for (int k = 128; k < 768; ++k) {
        float4 w0 = *(const float4*)(Wp + (size_t)k * 128 + j4);
        float4 w1 = *(const float4*)(Wp + (size_t)(k + 640) * 128 + j4);
        float4 w2 = *(const float4*)(Wp + (size_t)(k + 1280) * 128 + j4);
        float a0 = At[rrow][k], a1 = At[rrow + 8][k];
        fma4(acc0[0], a0, w0); fma4(acc0[1], a1, w0);
        fma4(acc1[0], a0, w1); fma4(acc1[1], a1, w1);
        fma4(acc2[0], a0, w2); fma4(acc2[1], a1, w2);
    }

    float4 bj = *(const float4*)(bpost + j4);
    float ps[4] = {0.f, 0.f, 0.f, 0.f}, pq[4] = {0.f, 0.f, 0.f, 0.f};
    #pragma unroll
    for (int r2 = 0; r2 < 2; ++r2) {
        int r = rrow + r2 * 8;
        int v = v0 + r;
        float f1 = f1s[r], f2 = f2s[r], sn = snorm[v];
        float4 o;
        o.x = (acc0[r2].x + bj.x + f1 * acc1[r2].x + f2 * acc2[r2].x) * sn;
        o.y = (acc0[r2].y + bj.y + f1 * acc1[r2].y + f2 * acc2[r2].y) * sn;
        o.z = (acc0[r2].z + bj.z + f1 * acc1[r2].z + f2 * acc2[r2].z) * sn;
        o.w = (acc0[r2].w + bj.w + f1 * acc1[r2].w + f2 * acc2[r2].w) * sn;
        *(float4*)(out + (size_t)v * 128 + j4) = o;
        ps[0] += o.x; pq[0] += o.x * o.x;
        ps[1] += o.y; pq[1] += o.y * o.y;
        ps[2] += o.z; pq[2] += o.z * o.z;
        ps[3] += o.w; pq[3] += o.w * o.w;
    }

    __syncthreads();                    // all At reads complete
    float* redS = &At[0][0];            // alias dead A-tile: [8][128]
    float* redQ = redS + 1024;          // [8][128]
    #pragma unroll
    for (int c = 0; c < 4; ++c) {
        redS[rrow * 128 + j4 + c] = ps[c];
        redQ[rrow * 128 + j4 + c] = pq[c];
    }
    __syncthreads();
    if (tid < 128) {
        float s = 0.f, q = 0.f;
        #pragma unroll
        for (int g = 0; g < 8; ++g) { s += redS[g * 128 + tid]; q += redQ[g * 128 + tid]; }
        atomicAdd(&colsum[tid], s);
        atomicAdd(&colsq[tid], q);
    }
}

// ---------------- column batch-norm ----------------
__global__ void k_norm(float* __restrict__ out, const float* __restrict__ colsum,
                       const float* __restrict__ colsq, const float* __restrict__ gamma,
                       const float* __restrict__ beta) {
    int i = blockIdx.x * 256 + threadIdx.x;
    if (i >= NN * 128) return;
    int j = i & 127;
    float mu = colsum[j] * (1.f / NN);
    float var = fmaxf(colsq[j] * (1.f / NN) - mu * mu, 0.f);
    float inv = 1.f / sqrtf(var + 1e-5f);
    out[i] = (out[i] - mu) * inv * gamma[j] + beta[j];
}

static inline size_t align256(size_t x) { return (x + 255) & ~(size_t)255; }

extern "C" void kernel_launch(void* const* d_in, const int* in_sizes, int n_in,
                              void* d_out, int out_size, void* d_ws, size_t ws_size,
                              hipStream_t stream) {
    const float* h      = (const float*)d_in[0];
    const float* eig    = (const float*)d_in[1];
    const float* ef     = (const float*)d_in[2];
    const int*   src    = (const int*)d_in[3];
    const int*   dst    = (const int*)d_in[4];
    const float* snorm  = (const float*)d_in[5];
    const float* W_pre  = (const float*)d_in[6];
    const float* b_pre  = (const float*)d_in[7];
    const float* ftW1   = (const float*)d_in[8];
    const float* ftb1   = (const float*)d_in[9];
    const float* ftW2   = (const float*)d_in[10];
    const float* ftb2   = (const float*)d_in[11];
    const float* ftW3   = (const float*)d_in[12];
    const float* ftb3   = (const float*)d_in[13];
    const float* W_post = (const float*)d_in[14];
    const float* b_post = (const float*)d_in[15];
    const float* gamma  = (const float*)d_in[16];
    const float* beta   = (const float*)d_in[17];
    float* out = (float*)d_out;

    char* ws = (char*)d_ws;
    size_t off = 0;
    int* rowptr   = (int*)(ws + off); off += align256((NN + 1) * 4);
    int* cursor   = (int*)(ws + off); off += align256(NN * 4);
    int* deg      = (int*)(ws + off); off += align256(NN * 4);
    int* csr_src  = (int*)(ws + off); off += align256((size_t)EE * 4);
    int* csr_eid  = (int*)(ws + off); off += align256((size_t)EE * 4);
    float* csr_wl = (float*)(ws + off); off += align256((size_t)EE * 4);
    float* colsum = (float*)(ws + off); off += 512;
    float* colsq  = (float*)(ws + off); off += 512;
    float* U      = (float*)(ws + off); off += (size_t)NN * 128 * 4;
    float* V      = (float*)(ws + off); off += (size_t)NN * 128 * 4;
    // total ~= 37 MB

    hipMemsetAsync(deg, 0, NN * 4, stream);
    hipMemsetAsync(colsum, 0, 1024, stream);   // colsum + colsq contiguous

    k_deg<<<1875, 256, 0, stream>>>(dst, deg);
    k_scan<<<1, 1024, 0, stream>>>(deg, rowptr, cursor);
    k_scatter<<<1875, 256, 0, stream>>>(src, dst, eig, ftW1, ftb1, ftW2, ftb2,
                                        ftW3, ftb3, cursor, csr_src, csr_eid, csr_wl);
    k_pre<<<1875, 256, 0, stream>>>(h, W_pre, U, V);
    k_fused<<<1875, 256, 0, stream>>>(h, U, V, ef, b_pre, W_pre, csr_src, rowptr,
                                      csr_eid, csr_wl, W_post, b_post, snorm, out,
                                      colsum, colsq);
    k_norm<<<15000, 256, 0, stream>>>(out, colsum, colsq, gamma, beta);
}